// Round 1
// baseline (1938.414 us; speedup 1.0000x reference)
//
#include <hip/hip_runtime.h>

// Sizes
#define B_ 1024
#define T_ 64
#define E_ 1024
#define A_ 10
#define S_ 30
#define H_ 200

typedef __attribute__((ext_vector_type(4))) float f32x4;
typedef __attribute__((ext_vector_type(8))) short s16x8;

__device__ __forceinline__ unsigned short f2bf(float f) {
  unsigned u = __float_as_uint(f);
  u = (u + 0x7FFFu + ((u >> 16) & 1u)) >> 16;
  return (unsigned short)u;
}
__device__ __forceinline__ float bf2f(unsigned short h) {
  return __uint_as_float(((unsigned)h) << 16);
}
__device__ __forceinline__ float eluf(float x) { return x > 0.f ? x : expm1f(x); }
__device__ __forceinline__ float sigmf(float x) { return 1.f / (1.f + expf(-x)); }
__device__ __forceinline__ float softpf(float x) { return x > 20.f ? x : log1pf(expf(x)); }

// ---- workspace layout (bytes) ----
// emb_pre (bf16)  [T*B][200]                        : 26,214,400
// wsbf    (bf16)  w1|wi|wh|i2|i3|o1d|o2 = 352,000 u16 : 704,000
// swz     (bf16)  MFMA-swizzled obs1_w embed part    : 425,984
#define OFF_WSBF 26214400
#define OFF_SWZ  (26214400 + 704000)

// --------------------------------------------------------------------------
// P1: convert weights to bf16 + build MFMA-swizzled B for the embed GEMM
// --------------------------------------------------------------------------
__global__ void prep_weights(const float* __restrict__ w1, const float* __restrict__ wi,
                             const float* __restrict__ wh, const float* __restrict__ i2,
                             const float* __restrict__ i3, const float* __restrict__ obs1w,
                             const float* __restrict__ o2,
                             unsigned short* __restrict__ wsbf,
                             unsigned short* __restrict__ swz) {
  int idx = blockIdx.x * blockDim.x + threadIdx.x;
  int stride = gridDim.x * blockDim.x;
  for (int i = idx; i < 352000; i += stride) {
    float v;
    if (i < 8000) v = w1[i];
    else if (i < 128000) v = wi[i - 8000];
    else if (i < 248000) v = wh[i - 128000];
    else if (i < 288000) v = i2[i - 248000];
    else if (i < 300000) v = i3[i - 288000];
    else if (i < 340000) v = obs1w[i - 300000];       // rows 0..199 of obs1_w
    else v = o2[i - 340000];
    wsbf[i] = f2bf(v);
  }
  // swz[((kc*13+nt)*64 + l)*8 + j] = obs1_w[200 + kc*32 + (l>>4)*8 + j][nt*16 + (l&15)]
  for (int i = idx; i < 212992; i += stride) {
    int j = i & 7;
    int l = (i >> 3) & 63;
    int rem = i >> 9;
    int nt = rem % 13, kc = rem / 13;
    int k = kc * 32 + ((l >> 4) * 8) + j;
    int n = nt * 16 + (l & 15);
    float v = (n < 200) ? obs1w[(size_t)(200 + k) * 200 + n] : 0.0f;
    swz[i] = f2bf(v);
  }
}

// --------------------------------------------------------------------------
// P2: emb_pre[t*B+b][n] = bf16( embed[b,t,:] @ obs1_w[200:,:]  + obs1_b[n] )
// MFMA 16x16x32 bf16, block = 64 rows x 208 cols (13 N-tiles), 4 waves.
// --------------------------------------------------------------------------
__global__ __launch_bounds__(256) void emb_gemm(const float* __restrict__ embed,
                                                const float* __restrict__ obs1b,
                                                const unsigned short* __restrict__ swz,
                                                unsigned short* __restrict__ emb_pre) {
  __shared__ __align__(16) unsigned short lds_A[64][40];  // 80B row stride
  int tid = threadIdx.x;
  int lane = tid & 63, w = tid >> 6;
  int R0 = blockIdx.x * 64;
  int tt = R0 >> 10;       // t
  int bb = R0 & 1023;      // base b

  f32x4 acc[13];
#pragma unroll
  for (int nt = 0; nt < 13; ++nt) acc[nt] = (f32x4){0.f, 0.f, 0.f, 0.f};

  int i_row = tid >> 2, cg = tid & 3;
  const float* arow = embed + ((size_t)(bb + i_row) * 64 + tt) * 1024 + cg * 8;

  for (int kc = 0; kc < 32; ++kc) {
    __syncthreads();
    {
      const float* p = arow + kc * 32;
      f32x4 a0 = *(const f32x4*)p;
      f32x4 a1 = *(const f32x4*)(p + 4);
      unsigned short* dst = &lds_A[i_row][cg * 8];
      dst[0] = f2bf(a0[0]); dst[1] = f2bf(a0[1]); dst[2] = f2bf(a0[2]); dst[3] = f2bf(a0[3]);
      dst[4] = f2bf(a1[0]); dst[5] = f2bf(a1[1]); dst[6] = f2bf(a1[2]); dst[7] = f2bf(a1[3]);
    }
    __syncthreads();
    s16x8 af = *(const s16x8*)&lds_A[w * 16 + (lane & 15)][(lane >> 4) * 8];
    const unsigned short* bp = swz + (size_t)kc * 6656 + (size_t)lane * 8;
#pragma unroll
    for (int nt = 0; nt < 13; ++nt) {
      s16x8 bfv = *(const s16x8*)(bp + nt * 512);
      acc[nt] = __builtin_amdgcn_mfma_f32_16x16x32_bf16(af, bfv, acc[nt], 0, 0, 0);
    }
  }
  int r0 = R0 + w * 16 + ((lane >> 4) << 2);
  int c0 = lane & 15;
#pragma unroll
  for (int nt = 0; nt < 13; ++nt) {
    int n = nt * 16 + c0;
    if (n < 200) {
      float bv = obs1b[n];
#pragma unroll
      for (int rr = 0; rr < 4; ++rr)
        emb_pre[(size_t)(r0 + rr) * 200 + n] = f2bf(acc[nt][rr] + bv);
    }
  }
}

// --------------------------------------------------------------------------
// Scan: 256 blocks x 640 threads; each block owns 4 batch rows for all T.
// Activations in LDS laid out [N][4] (rows innermost, float4 per col).
// --------------------------------------------------------------------------
__global__ __launch_bounds__(640) void scan_kernel(
    const float* __restrict__ action, const float* __restrict__ eps_post,
    const float* __restrict__ eps_prior, const float* __restrict__ img1_b,
    const float* __restrict__ gru_bi, const float* __restrict__ gru_bh,
    const float* __restrict__ img2_b, const float* __restrict__ img3_b,
    const float* __restrict__ obs2_b, const unsigned short* __restrict__ wsbf,
    const unsigned short* __restrict__ emb_pre, float* __restrict__ out) {
  __shared__ __align__(16) float s_stoch[30][4];
  __shared__ __align__(16) float s_act[10][4];
  __shared__ __align__(16) float s_x[200][4];
  __shared__ __align__(16) float s_gi[600][4];
  __shared__ __align__(16) float s_gh[600][4];
  __shared__ __align__(16) float s_deter[200][4];
  __shared__ __align__(16) float s_y1[200][4];
  __shared__ __align__(16) float s_o1[200][4];
  __shared__ __align__(16) float s_p5[2][5][60][4];
  __shared__ __align__(16) float s_y[60][4];
  __shared__ __align__(16) float s_o[60][4];

  const unsigned short* w1  = wsbf;            // [40][200]
  const unsigned short* wi  = wsbf + 8000;     // [200][600]
  const unsigned short* wh  = wsbf + 128000;   // [200][600]
  const unsigned short* i2w = wsbf + 248000;   // [200][200]
  const unsigned short* i3w = wsbf + 288000;   // [200][60]
  const unsigned short* o1d = wsbf + 300000;   // [200][200]
  const unsigned short* o2w = wsbf + 340000;   // [200][60]

  int tid = threadIdx.x;
  int b0 = blockIdx.x * 4;

  for (int i = tid; i < 30 * 4; i += 640) ((float*)s_stoch)[i] = 0.f;
  for (int i = tid; i < 200 * 4; i += 640) ((float*)s_deter)[i] = 0.f;
  __syncthreads();

  for (int t = 0; t < T_; ++t) {
    // load action rows
    if (tid < 40) {
      int k = tid % 10, r = tid / 10;
      s_act[k][r] = action[((size_t)(b0 + r) * T_ + t) * A_ + k];
    }
    __syncthreads();

    // stage1: x = elu([stoch, act] @ img1_w + img1_b)
    if (tid < 200) {
      int n = tid;
      float bv = img1_b[n];
      f32x4 a = {bv, bv, bv, bv};
#pragma unroll 5
      for (int k = 0; k < 30; ++k) {
        f32x4 s = *(const f32x4*)s_stoch[k];
        a += s * bf2f(w1[k * 200 + n]);
      }
#pragma unroll 5
      for (int k = 0; k < 10; ++k) {
        f32x4 v = *(const f32x4*)s_act[k];
        a += v * bf2f(w1[(30 + k) * 200 + n]);
      }
      f32x4 x;
#pragma unroll
      for (int r = 0; r < 4; ++r) x[r] = eluf(a[r]);
      *(f32x4*)s_x[n] = x;
    }
    __syncthreads();

    // stage2: gi = x@wi + bi ; gh = deter@wh + bh
    if (tid < 600) {
      int n = tid;
      const unsigned short* pwi = wi + n;
      const unsigned short* pwh = wh + n;
      float biv = gru_bi[n], bhv = gru_bh[n];
      f32x4 ai = {biv, biv, biv, biv};
      f32x4 ah = {bhv, bhv, bhv, bhv};
#pragma unroll 4
      for (int k = 0; k < 200; ++k) {
        f32x4 xv = *(const f32x4*)s_x[k];
        f32x4 dv = *(const f32x4*)s_deter[k];
        ai += xv * bf2f(pwi[k * 600]);
        ah += dv * bf2f(pwh[k * 600]);
      }
      *(f32x4*)s_gi[n] = ai;
      *(f32x4*)s_gh[n] = ah;
    }
    __syncthreads();

    // stage3: GRU elementwise -> deter (in place)
    if (tid < 200) {
      int n = tid;
      f32x4 gr = *(const f32x4*)s_gi[n];
      f32x4 gz = *(const f32x4*)s_gi[n + 200];
      f32x4 gn = *(const f32x4*)s_gi[n + 400];
      f32x4 hr = *(const f32x4*)s_gh[n];
      f32x4 hz = *(const f32x4*)s_gh[n + 200];
      f32x4 hn = *(const f32x4*)s_gh[n + 400];
      f32x4 dv = *(const f32x4*)s_deter[n];
      f32x4 dn;
#pragma unroll
      for (int r = 0; r < 4; ++r) {
        float rr = sigmf(gr[r] + hr[r]);
        float zz = sigmf(gz[r] + hz[r]);
        float nn = tanhf(gn[r] + rr * hn[r]);
        dn[r] = (1.f - zz) * nn + zz * dv[r];
      }
      *(f32x4*)s_deter[n] = dn;
    }
    __syncthreads();

    // stage4: y1 = elu(deter@img2 + b2) ; o1 = elu(deter@obs1d + emb_pre)
    if (tid < 400) {
      int sel = tid >= 200;
      int n = sel ? tid - 200 : tid;
      const unsigned short* W = (sel ? o1d : i2w) + n;
      f32x4 a;
      if (sel) a = (f32x4){0.f, 0.f, 0.f, 0.f};
      else { float bv = img2_b[n]; a = (f32x4){bv, bv, bv, bv}; }
#pragma unroll 4
      for (int k = 0; k < 200; ++k) {
        f32x4 dv = *(const f32x4*)s_deter[k];
        a += dv * bf2f(W[k * 200]);
      }
      if (sel) {
        size_t eb = ((size_t)t * 1024 + b0) * 200 + n;
        f32x4 o1v;
#pragma unroll
        for (int r = 0; r < 4; ++r) o1v[r] = eluf(a[r] + bf2f(emb_pre[eb + (size_t)r * 200]));
        *(f32x4*)s_o1[n] = o1v;
      } else {
        f32x4 y1v;
#pragma unroll
        for (int r = 0; r < 4; ++r) y1v[r] = eluf(a[r]);
        *(f32x4*)s_y1[n] = y1v;
      }
    }
    __syncthreads();

    // stage5a: partial K-split matvecs for y = y1@img3, o = o1@obs2
    if (tid < 600) {
      int n = tid % 60;
      int g = tid / 60;        // 0..9
      int sel = g & 1, ks = g >> 1;  // ks 0..4
      const unsigned short* W = (sel ? o2w : i3w) + n;
      const float(*src)[4] = sel ? s_o1 : s_y1;
      f32x4 a = {0.f, 0.f, 0.f, 0.f};
      int k0 = ks * 40;
#pragma unroll 4
      for (int k = k0; k < k0 + 40; ++k) {
        f32x4 v = *(const f32x4*)src[k];
        a += v * bf2f(W[k * 60]);
      }
      *(f32x4*)s_p5[sel][ks][n] = a;
    }
    __syncthreads();

    // stage5b: reduce partials + bias
    if (tid < 120) {
      int n = tid % 60, sel = tid / 60;
      float bv = sel ? obs2_b[n] : img3_b[n];
      f32x4 a = {bv, bv, bv, bv};
#pragma unroll
      for (int ks = 0; ks < 5; ++ks) a += *(const f32x4*)s_p5[sel][ks][n];
      if (sel) *(f32x4*)s_o[n] = a;
      else *(f32x4*)s_y[n] = a;
    }
    __syncthreads();

    // stage6: distributions, sampling, output writes, carry update
    if (tid < 120) {
      int r = tid / 30, j = tid % 30;
      int b = b0 + r;
      size_t base = ((size_t)b * T_ + t) * 580;
      size_t eoff = ((size_t)t * 1024 + b) * 30 + j;
      float qm = s_o[j][r];
      float qs = softpf(s_o[j + 30][r]) + 0.1f;
      float qst = qm + qs * eps_post[eoff];
      out[base + j] = qm;
      out[base + 30 + j] = qs;
      out[base + 60 + j] = qst;
      s_stoch[j][r] = qst;
      float pm = s_y[j][r];
      float ps = softpf(s_y[j + 30][r]) + 0.1f;
      float pst = pm + ps * eps_prior[eoff];
      out[base + 290 + j] = pm;
      out[base + 320 + j] = ps;
      out[base + 350 + j] = pst;
    }
    for (int idx = tid; idx < 800; idx += 640) {
      int n = idx % 200, r = idx / 200;
      float v = s_deter[n][r];
      size_t base = ((size_t)(b0 + r) * T_ + t) * 580;
      out[base + 90 + n] = v;
      out[base + 380 + n] = v;
    }
    __syncthreads();
  }
}

extern "C" void kernel_launch(void* const* d_in, const int* in_sizes, int n_in,
                              void* d_out, int out_size, void* d_ws, size_t ws_size,
                              hipStream_t stream) {
  const float* embed    = (const float*)d_in[0];
  const float* action   = (const float*)d_in[1];
  const float* eps_post = (const float*)d_in[2];
  const float* eps_prior= (const float*)d_in[3];
  const float* img1_w   = (const float*)d_in[4];
  const float* img1_b   = (const float*)d_in[5];
  const float* gru_wi   = (const float*)d_in[6];
  const float* gru_wh   = (const float*)d_in[7];
  const float* gru_bi   = (const float*)d_in[8];
  const float* gru_bh   = (const float*)d_in[9];
  const float* img2_w   = (const float*)d_in[10];
  const float* img2_b   = (const float*)d_in[11];
  const float* img3_w   = (const float*)d_in[12];
  const float* img3_b   = (const float*)d_in[13];
  const float* obs1_w   = (const float*)d_in[14];
  const float* obs1_b   = (const float*)d_in[15];
  const float* obs2_w   = (const float*)d_in[16];
  const float* obs2_b   = (const float*)d_in[17];

  char* ws = (char*)d_ws;
  unsigned short* emb_pre = (unsigned short*)ws;
  unsigned short* wsbf    = (unsigned short*)(ws + OFF_WSBF);
  unsigned short* swz     = (unsigned short*)(ws + OFF_SWZ);
  float* outp = (float*)d_out;

  prep_weights<<<256, 256, 0, stream>>>(img1_w, gru_wi, gru_wh, img2_w, img3_w,
                                        obs1_w, obs2_w, wsbf, swz);
  emb_gemm<<<1024, 256, 0, stream>>>(embed, obs1_b, swz, emb_pre);
  scan_kernel<<<256, 640, 0, stream>>>(action, eps_post, eps_prior, img1_b, gru_bi,
                                       gru_bh, img2_b, img3_b, obs2_b, wsbf,
                                       emb_pre, outp);
}